// Round 3
// baseline (583.474 us; speedup 1.0000x reference)
//
#include <hip/hip_runtime.h>

// GAT node regressor: 3 GAT layers (HID=64, 4 heads x 16) + linear head.
// CSR-by-dst built once per call via ATOMIC scatter (deg hist -> 3-phase scan
// -> phantom fill -> atomic scatter), with per-node ranges PADDED to x4
// (pad edges -> phantom node n: als[n]=-1e30 so pe==0 exactly; xh row n = 0).
// Per layer:
//   k_mgemm: xh = h@W on MATRIX CORES via bf16 hi/lo split (fp32 emulation).
//            Wave = 16 nodes x 64 cols, K-step 32, no LDS; W pre-packed by
//            k_wprep. Fused al_s/al_d logits + per-node softmax shift
//            m = lrelu(als+ald) via intra-quad shuffles.
//   k_agg : 4 dst nodes per wave over the padded CSR, SOFTWARE-PIPELINED:
//           chunk i+1's global loads (ssrc -> dependent als[u] gather, ald/m
//           by nid) issue before chunk i's accumulate, hiding the edge-phase
//           latency chain under the gather bursts. Stash (u, pe4)
//           head-transposed in LDS (same-wave RAW, in-order DS unit, no
//           barrier). Accumulate: aligned 4-edge groups, 4-group unroll = 16
//           coalesced 256B row gathers in flight, 2 fmac chains per node.
//           Layer 2 fuses h@out_w via shuffle.

#define SCB 2048  // nodes per scan block

typedef __attribute__((ext_vector_type(8))) short bf16x8;
typedef __attribute__((ext_vector_type(4))) float f32x4;

__device__ inline unsigned short bf16_rtn(float x) {
    union { float f; unsigned u; } a; a.f = x;
    return (unsigned short)((a.u + 0x7FFFu + ((a.u >> 16) & 1u)) >> 16);
}
__device__ inline float bf16_to_f(unsigned short s) {
    union { unsigned u; float f; } b; b.u = ((unsigned)s) << 16;
    return b.f;
}

// zero deg + init phantom node: als[n]=-1e30 (=> pe 0), xh row n = 0.
__global__ __launch_bounds__(256) void k_init(int* __restrict__ deg,
                                              float* __restrict__ als, float* __restrict__ xh, int n) {
    int i = blockIdx.x * 256 + threadIdx.x;
    if (i < n) deg[i] = 0;
    if (i < 4) als[(size_t)n * 4 + i] = -1e30f;
    if (i < 64) xh[(size_t)n * 64 + i] = 0.f;
}

__global__ __launch_bounds__(256) void k_deg(const int* __restrict__ dst, int* __restrict__ deg, int e) {
    int i = blockIdx.x * 256 + threadIdx.x;
    if (i < e) atomicAdd(&deg[dst[i]], 1);
}

// Per-block (2048 nodes) exclusive scan of padded degrees; local offsets to
// loc[], block totals to bsum[].
__global__ __launch_bounds__(256) void k_scan1(const int* __restrict__ deg, int* __restrict__ loc,
                                               int* __restrict__ bsum, int n) {
    __shared__ int ts[256];
    int b = blockIdx.x, t = threadIdx.x;
    int base = b * SCB + t * 8;
    int d[8], s = 0;
    if (base + 8 <= n) {
        int4 a = *(const int4*)(deg + base);
        int4 c = *(const int4*)(deg + base + 4);
        int dv[8] = {a.x, a.y, a.z, a.w, c.x, c.y, c.z, c.w};
#pragma unroll
        for (int k = 0; k < 8; ++k) { d[k] = s; s += (dv[k] + 3) & ~3; }
    } else {
#pragma unroll
        for (int k = 0; k < 8; ++k) {
            d[k] = s;
            int v = (base + k < n) ? deg[base + k] : 0;
            s += (v + 3) & ~3;
        }
    }
    ts[t] = s;
    __syncthreads();
    for (int o = 1; o < 256; o <<= 1) {
        int add = (t >= o) ? ts[t - o] : 0;
        __syncthreads();
        ts[t] += add;
        __syncthreads();
    }
    int excl = ts[t] - s;
    if (base + 8 <= n) {
        int4 o0 = {excl + d[0], excl + d[1], excl + d[2], excl + d[3]};
        int4 o1 = {excl + d[4], excl + d[5], excl + d[6], excl + d[7]};
        *(int4*)(loc + base) = o0;
        *(int4*)(loc + base + 4) = o1;
    } else {
        for (int k = 0; k < 8; ++k)
            if (base + k < n) loc[base + k] = excl + d[k];
    }
    if (t == 255) bsum[b] = ts[255];
}

// Single-wave inclusive scan of block sums (nb <= 64).
__global__ __launch_bounds__(64) void k_scan2(int* __restrict__ bsum, int nb) {
    int t = threadIdx.x;
    int v = (t < nb) ? bsum[t] : 0;
#pragma unroll
    for (int o = 1; o < 64; o <<= 1) {
        int u = __shfl_up(v, o, 64);
        if (t >= o) v += u;
    }
    if (t < nb) bsum[t] = v;
}

__global__ __launch_bounds__(256) void k_scan3(const int* __restrict__ deg, const int* __restrict__ loc,
                                               const int* __restrict__ bsum, int* __restrict__ poffs,
                                               int* __restrict__ pend, int* __restrict__ cursor, int n) {
    int i = blockIdx.x * 256 + threadIdx.x;
    if (i >= n) return;
    int b = i >> 11;  // SCB = 2048
    int base = b ? bsum[b - 1] : 0;
    int p = base + loc[i];
    int d4 = (deg[i] + 3) & ~3;
    poffs[i] = p;
    pend[i] = p + d4;
    cursor[i] = p;
}

// Pre-fill padded ssrc with phantom n (int4-wide).
__global__ __launch_bounds__(256) void k_fill(int4* __restrict__ ssrc4, int n, int tot4) {
    int i = blockIdx.x * 256 + threadIdx.x;
    if (i < tot4) ssrc4[i] = (int4){n, n, n, n};
}

__global__ __launch_bounds__(256) void k_scatter(const int* __restrict__ src, const int* __restrict__ dst,
                                                 int* __restrict__ cursor, int* __restrict__ ssrc, int e) {
    int i = blockIdx.x * 256 + threadIdx.x;
    if (i >= e) return;
    int d = dst[i];
    int p = atomicAdd(&cursor[d], 1);
    ssrc[p] = src[i];
}

// Pack all three layers' W (fp32 [D][64]) into MFMA B-fragment order, hi/lo
// bf16: pack[((ko*64)+n)*8 + j] = bf16(W[ko*8+j][n]). One thread per (ko,n).
__global__ __launch_bounds__(256) void k_wprep(const float* __restrict__ w0, const float* __restrict__ w1,
                                               const float* __restrict__ w2,
                                               unsigned short* __restrict__ p0h, unsigned short* __restrict__ p0l,
                                               unsigned short* __restrict__ p1h, unsigned short* __restrict__ p1l,
                                               unsigned short* __restrict__ p2h, unsigned short* __restrict__ p2l) {
    int g = blockIdx.x * 256 + threadIdx.x;
    const float* W;
    unsigned short *ph, *pl;
    int idx;
    if (g < 1024) { W = w0; ph = p0h; pl = p0l; idx = g; }          // D=128: ko 0..15
    else if (g < 1536) { W = w1; ph = p1h; pl = p1l; idx = g - 1024; }  // D=64: ko 0..7
    else if (g < 2048) { W = w2; ph = p2h; pl = p2l; idx = g - 1536; }
    else return;
    int ko = idx >> 6, nn = idx & 63;
#pragma unroll
    for (int j = 0; j < 8; ++j) {
        float w = W[(size_t)(ko * 8 + j) * 64 + nn];
        unsigned short hb = bf16_rtn(w);
        ph[(size_t)idx * 8 + j] = hb;
        pl[(size_t)idx * 8 + j] = bf16_rtn(w - bf16_to_f(hb));
    }
}

// xh = h @ W via MFMA, fused attention logits + per-node softmax shift m.
template <int D_IN>
__global__ __launch_bounds__(256) void k_mgemm(const float* __restrict__ h,
                                               const unsigned short* __restrict__ wph,
                                               const unsigned short* __restrict__ wpl,
                                               const float* __restrict__ asrc, const float* __restrict__ adst,
                                               float* __restrict__ xh, float* __restrict__ als,
                                               float* __restrict__ ald, float* __restrict__ mvec, int n) {
    int t = threadIdx.x;
    int wv = t >> 6, lane = t & 63;
    int quad = lane >> 4, l16 = lane & 15;
    int m0 = blockIdx.x * 64 + wv * 16;
    int node_a = m0 + l16;
    int mm = min(node_a, n - 1);
    const float* hrow = h + (size_t)mm * D_IN + quad * 8;

    f32x4 acc[4];
#pragma unroll
    for (int i = 0; i < 4; ++i) acc[i] = (f32x4){0.f, 0.f, 0.f, 0.f};

    constexpr int KSTEPS = D_IN / 32;
#pragma unroll
    for (int s = 0; s < KSTEPS; ++s) {
        float4 a0 = *(const float4*)(hrow + s * 32);
        float4 a1 = *(const float4*)(hrow + s * 32 + 4);
        float av[8] = {a0.x, a0.y, a0.z, a0.w, a1.x, a1.y, a1.z, a1.w};
        bf16x8 ahi, alo;
#pragma unroll
        for (int j = 0; j < 8; ++j) {
            unsigned short hb = bf16_rtn(av[j]);
            ahi[j] = (short)hb;
            alo[j] = (short)bf16_rtn(av[j] - bf16_to_f(hb));
        }
        const unsigned short* bbase = wph + ((size_t)((s * 4 + quad) * 64 + l16)) * 8;
        const unsigned short* bbasel = wpl + ((size_t)((s * 4 + quad) * 64 + l16)) * 8;
#pragma unroll
        for (int nt = 0; nt < 4; ++nt) {
            bf16x8 bhi = *(const bf16x8*)(bbase + (size_t)nt * 16 * 8);
            bf16x8 blo = *(const bf16x8*)(bbasel + (size_t)nt * 16 * 8);
            acc[nt] = __builtin_amdgcn_mfma_f32_16x16x32_bf16(ahi, bhi, acc[nt], 0, 0, 0);
            acc[nt] = __builtin_amdgcn_mfma_f32_16x16x32_bf16(ahi, blo, acc[nt], 0, 0, 0);
            acc[nt] = __builtin_amdgcn_mfma_f32_16x16x32_bf16(alo, bhi, acc[nt], 0, 0, 0);
        }
    }
    // epilogue: store xh + fused logits (head == N-tile: 16 cols/head)
#pragma unroll
    for (int nt = 0; nt < 4; ++nt) {
        float as_l = asrc[nt * 16 + l16];
        float ad_l = adst[nt * 16 + l16];
#pragma unroll
        for (int r = 0; r < 4; ++r) {
            int node = m0 + quad * 4 + r;
            float c = acc[nt][r];
            if (node < n) xh[(size_t)node * 64 + nt * 16 + l16] = c;
            float ps = c * as_l, pd = c * ad_l;
            ps += __shfl_xor(ps, 1, 64); pd += __shfl_xor(pd, 1, 64);
            ps += __shfl_xor(ps, 2, 64); pd += __shfl_xor(pd, 2, 64);
            ps += __shfl_xor(ps, 4, 64); pd += __shfl_xor(pd, 4, 64);
            ps += __shfl_xor(ps, 8, 64); pd += __shfl_xor(pd, 8, 64);
            if (l16 == 0 && node < n) {
                als[node * 4 + nt] = ps;
                ald[node * 4 + nt] = pd;
                float sm = ps + pd;
                mvec[node * 4 + nt] = sm >= 0.f ? sm : 0.2f * sm;
            }
        }
    }
}

__device__ inline float4 lrelu4(float4 v) {
    float4 r;
    r.x = v.x >= 0.f ? v.x : 0.2f * v.x;
    r.y = v.y >= 0.f ? v.y : 0.2f * v.y;
    r.z = v.z >= 0.f ? v.z : 0.2f * v.z;
    r.w = v.w >= 0.f ? v.w : 0.2f * v.w;
    return r;
}

// Aligned accumulate over [LO,HI) within chunk starting at s0; two fmac
// chains per node (ACCA/ACCB) to halve dependency stalls.
#define ACCUM(LO, HI, ACCA, ACCB, ZS)                                           \
    {                                                                           \
        int g_ = ((LO) - s0) >> 2, gb_ = ((HI) - s0) >> 2;                      \
        for (; g_ + 4 <= gb_; g_ += 4) {                                        \
            int4 uu0 = *(const int4*)&ub[g_ * 4];                               \
            int4 uu1 = *(const int4*)&ub[g_ * 4 + 4];                           \
            int4 uu2 = *(const int4*)&ub[g_ * 4 + 8];                           \
            int4 uu3 = *(const int4*)&ub[g_ * 4 + 12];                          \
            float4 pp0 = *(const float4*)&per[g_ * 4];                          \
            float4 pp1 = *(const float4*)&per[g_ * 4 + 4];                      \
            float4 pp2 = *(const float4*)&per[g_ * 4 + 8];                      \
            float4 pp3 = *(const float4*)&per[g_ * 4 + 12];                     \
            float x0 = *(const float*)(xl + (size_t)(unsigned)uu0.x);           \
            float x1 = *(const float*)(xl + (size_t)(unsigned)uu0.y);           \
            float x2 = *(const float*)(xl + (size_t)(unsigned)uu0.z);           \
            float x3 = *(const float*)(xl + (size_t)(unsigned)uu0.w);           \
            float x4 = *(const float*)(xl + (size_t)(unsigned)uu1.x);           \
            float x5 = *(const float*)(xl + (size_t)(unsigned)uu1.y);           \
            float x6 = *(const float*)(xl + (size_t)(unsigned)uu1.z);           \
            float x7 = *(const float*)(xl + (size_t)(unsigned)uu1.w);           \
            float x8 = *(const float*)(xl + (size_t)(unsigned)uu2.x);           \
            float x9 = *(const float*)(xl + (size_t)(unsigned)uu2.y);           \
            float xa = *(const float*)(xl + (size_t)(unsigned)uu2.z);           \
            float xb = *(const float*)(xl + (size_t)(unsigned)uu2.w);           \
            float xc = *(const float*)(xl + (size_t)(unsigned)uu3.x);           \
            float xd = *(const float*)(xl + (size_t)(unsigned)uu3.y);           \
            float xe = *(const float*)(xl + (size_t)(unsigned)uu3.z);           \
            float xf = *(const float*)(xl + (size_t)(unsigned)uu3.w);           \
            ZS += pp0.x + pp0.y + pp0.z + pp0.w;                                \
            ZS += pp1.x + pp1.y + pp1.z + pp1.w;                                \
            ZS += pp2.x + pp2.y + pp2.z + pp2.w;                                \
            ZS += pp3.x + pp3.y + pp3.z + pp3.w;                                \
            ACCA += pp0.x * x0; ACCB += pp0.y * x1;                             \
            ACCA += pp0.z * x2; ACCB += pp0.w * x3;                             \
            ACCA += pp1.x * x4; ACCB += pp1.y * x5;                             \
            ACCA += pp1.z * x6; ACCB += pp1.w * x7;                             \
            ACCA += pp2.x * x8; ACCB += pp2.y * x9;                             \
            ACCA += pp2.z * xa; ACCB += pp2.w * xb;                             \
            ACCA += pp3.x * xc; ACCB += pp3.y * xd;                             \
            ACCA += pp3.z * xe; ACCB += pp3.w * xf;                             \
        }                                                                       \
        for (; g_ < gb_; ++g_) {                                                \
            int4 uu = *(const int4*)&ub[g_ * 4];                                \
            float4 pp = *(const float4*)&per[g_ * 4];                           \
            float x0 = *(const float*)(xl + (size_t)(unsigned)uu.x);            \
            float x1 = *(const float*)(xl + (size_t)(unsigned)uu.y);            \
            float x2 = *(const float*)(xl + (size_t)(unsigned)uu.z);            \
            float x3 = *(const float*)(xl + (size_t)(unsigned)uu.w);            \
            ZS += pp.x + pp.y + pp.z + pp.w;                                    \
            ACCA += pp.x * x0; ACCB += pp.y * x1;                               \
            ACCA += pp.z * x2; ACCB += pp.w * x3;                               \
        }                                                                       \
    }

__global__ __launch_bounds__(256) void k_agg(const float* __restrict__ xh,
                                             const float* __restrict__ als, const float* __restrict__ ald,
                                             const float* __restrict__ mvec,
                                             const int* __restrict__ poffs, const int* __restrict__ pend,
                                             const int* __restrict__ ssrc,
                                             const float* __restrict__ bias, float* __restrict__ hout,
                                             const float* __restrict__ outw, const float* __restrict__ outb,
                                             float* __restrict__ fout, int n) {
    __shared__ int s_u[4][64];
    __shared__ float s_pe[4][4][64];  // [wslot][head][edge]
    int wslot = threadIdx.x >> 6;
    int lane = threadIdx.x & 63;
    int w = (blockIdx.x * 256 + threadIdx.x) >> 6;
    int v0 = w << 2;
    if (v0 >= n) return;
    int head = lane >> 4;
    int* ub = s_u[wslot];
    float* per = s_pe[wslot][head];      // read row for my head
    float* pew = &s_pe[wslot][0][lane];  // write base, stride 64 per head

    int vlast = n - 1;
    int last = min(v0 + 3, vlast);
    int4 rr = *(const int4*)(poffs + v0);
    int e3 = pend[last];
    int r0 = rr.x;
    int r1 = (v0 + 1 <= last) ? rr.y : e3;
    int r2 = (v0 + 2 <= last) ? rr.z : e3;
    int r3 = (v0 + 3 <= last) ? rr.w : e3;

    const char* xl = (const char*)(xh + lane);  // lane column folded into base
    // self edges (pe = 1); issued up-front, all independent
    float acc0a = *(const float*)(xl + ((size_t)(unsigned)v0 << 8));
    float acc1a = *(const float*)(xl + ((size_t)(unsigned)min(v0 + 1, vlast) << 8));
    float acc2a = *(const float*)(xl + ((size_t)(unsigned)min(v0 + 2, vlast) << 8));
    float acc3a = *(const float*)(xl + ((size_t)(unsigned)min(v0 + 3, vlast) << 8));
    float acc0b = 0.f, acc1b = 0.f, acc2b = 0.f, acc3b = 0.f;
    float zs0 = 0.f, zs1 = 0.f, zs2 = 0.f, zs3 = 0.f;

    // prefetch chunk 0 (ssrc -> dependent als gather; ald/m by nid)
    int s0 = r0;
    int u_n = n;
    if (s0 < e3) {
        if (lane < e3 - s0) u_n = ssrc[s0 + lane];
    }
    float4 alu_n = *(const float4*)(als + 4 * (size_t)u_n);
    int e_n = s0 + lane;
    int nid_n = min(v0 + (e_n >= r1) + (e_n >= r2) + (e_n >= r3), vlast);
    float4 ald_n = *(const float4*)(ald + 4 * (size_t)nid_n);
    float4 m_n = *(const float4*)(mvec + 4 * (size_t)nid_n);

    while (s0 < e3) {
        int cnt = min(64, e3 - s0);
        // pe for current chunk from prefetched values
        float4 e4 = lrelu4(make_float4(alu_n.x + ald_n.x, alu_n.y + ald_n.y,
                                       alu_n.z + ald_n.z, alu_n.w + ald_n.w));
        float4 pe;
        pe.x = __expf(e4.x - m_n.x);
        pe.y = __expf(e4.y - m_n.y);
        pe.z = __expf(e4.z - m_n.z);
        pe.w = __expf(e4.w - m_n.w);
        ub[lane] = u_n << 8;  // row byte offset; pads point at phantom n
        pew[0] = pe.x;        // transposed stash: bank stride 64 -> 2-way, free
        pew[64] = pe.y;
        pew[128] = pe.z;
        pew[192] = pe.w;
        // issue next chunk's loads before the long accumulate phase
        int s1 = s0 + 64;
        if (s1 < e3) {
            u_n = n;
            if (lane < e3 - s1) u_n = ssrc[s1 + lane];
            alu_n = *(const float4*)(als + 4 * (size_t)u_n);
            int e1 = s1 + lane;
            int nid1 = min(v0 + (e1 >= r1) + (e1 >= r2) + (e1 >= r3), vlast);
            ald_n = *(const float4*)(ald + 4 * (size_t)nid1);
            m_n = *(const float4*)(mvec + 4 * (size_t)nid1);
        }
        // same-wave LDS RAW (in-order DS unit), no barrier needed
        int lim = s0 + cnt;
        int hi0 = min(r1, lim);
        int lo1 = max(r1, s0), hi1 = min(r2, lim);
        int lo2 = max(r2, s0), hi2 = min(r3, lim);
        int lo3 = max(r3, s0);
        ACCUM(s0, hi0, acc0a, acc0b, zs0);
        ACCUM(lo1, hi1, acc1a, acc1b, zs1);
        ACCUM(lo2, hi2, acc2a, acc2b, zs2);
        ACCUM(lo3, lim, acc3a, acc3b, zs3);
        s0 = s1;
    }

    float bl = bias[lane];
    float o0 = fmaxf((acc0a + acc0b) / (1.f + zs0 + 1e-16f) + bl, 0.f);
    float o1 = fmaxf((acc1a + acc1b) / (1.f + zs1 + 1e-16f) + bl, 0.f);
    float o2 = fmaxf((acc2a + acc2b) / (1.f + zs2 + 1e-16f) + bl, 0.f);
    float o3 = fmaxf((acc3a + acc3b) / (1.f + zs3 + 1e-16f) + bl, 0.f);
    if (outw) {
        float ow = outw[lane];
        float ob = outb[0];
        float t0 = o0 * ow, t1 = o1 * ow, t2 = o2 * ow, t3 = o3 * ow;
#pragma unroll
        for (int d = 32; d; d >>= 1) {
            t0 += __shfl_down(t0, d, 64);
            t1 += __shfl_down(t1, d, 64);
            t2 += __shfl_down(t2, d, 64);
            t3 += __shfl_down(t3, d, 64);
        }
        if (lane == 0) {
            fout[v0] = t0 + ob;
            if (v0 + 1 < n) fout[v0 + 1] = t1 + ob;
            if (v0 + 2 < n) fout[v0 + 2] = t2 + ob;
            if (v0 + 3 < n) fout[v0 + 3] = t3 + ob;
        }
    } else {
        hout[((size_t)v0 << 6) + lane] = o0;
        if (v0 + 1 < n) hout[((size_t)(v0 + 1) << 6) + lane] = o1;
        if (v0 + 2 < n) hout[((size_t)(v0 + 2) << 6) + lane] = o2;
        if (v0 + 3 < n) hout[((size_t)(v0 + 3) << 6) + lane] = o3;
    }
}

extern "C" void kernel_launch(void* const* d_in, const int* in_sizes, int n_in,
                              void* d_out, int out_size, void* d_ws, size_t ws_size,
                              hipStream_t stream) {
    const float* x = (const float*)d_in[0];
    const int* ei = (const int*)d_in[1];
    const float* w[3] = {(const float*)d_in[2], (const float*)d_in[6], (const float*)d_in[10]};
    const float* as[3] = {(const float*)d_in[3], (const float*)d_in[7], (const float*)d_in[11]};
    const float* ad[3] = {(const float*)d_in[4], (const float*)d_in[8], (const float*)d_in[12]};
    const float* b[3] = {(const float*)d_in[5], (const float*)d_in[9], (const float*)d_in[13]};
    const float* outw = (const float*)d_in[14];
    const float* outb = (const float*)d_in[15];

    const int N = in_sizes[0] / 128;
    const int E = in_sizes[1] / 2;
    const int* src = ei;
    const int* dst = ei + E;
    const int NS1 = (N + SCB - 1) / SCB;  // 49 scan blocks
    const int SS = E + 3 * N + 256;       // padded edge-array capacity

    char* ws = (char*)d_ws;
    auto alloc = [&](size_t bytes) -> void* {
        void* p = (void*)ws;
        ws += (bytes + 255) & ~(size_t)255;
        return p;
    };
    int* deg = (int*)alloc((size_t)N * 4);
    int* loc = (int*)alloc((size_t)N * 4);
    int* bsum = (int*)alloc(64 * 4);
    int* poffs = (int*)alloc((size_t)(N + 8) * 4);
    int* pend = (int*)alloc((size_t)N * 4);
    int* cursor = (int*)alloc((size_t)N * 4);
    int* ssrc = (int*)alloc((size_t)SS * 4);
    float* xh = (float*)alloc((size_t)(N + 1) * 64 * 4);  // +1: phantom zero row
    float* hbuf = (float*)alloc((size_t)N * 64 * 4);
    float* als = (float*)alloc((size_t)(N + 1) * 4 * 4);  // +1: phantom -1e30
    float* ald = (float*)alloc((size_t)N * 4 * 4);
    float* mvec = (float*)alloc((size_t)N * 4 * 4);
    unsigned short* p0h = (unsigned short*)alloc(8192 * 2);
    unsigned short* p0l = (unsigned short*)alloc(8192 * 2);
    unsigned short* p1h = (unsigned short*)alloc(4096 * 2);
    unsigned short* p1l = (unsigned short*)alloc(4096 * 2);
    unsigned short* p2h = (unsigned short*)alloc(4096 * 2);
    unsigned short* p2l = (unsigned short*)alloc(4096 * 2);

    const int nblk = (N + 255) / 256;
    const int eblk = (E + 255) / 256;

    k_wprep<<<8, 256, 0, stream>>>(w[0], w[1], w[2], p0h, p0l, p1h, p1l, p2h, p2l);
    k_init<<<nblk, 256, 0, stream>>>(deg, als, xh, N);
    k_deg<<<eblk, 256, 0, stream>>>(dst, deg, E);
    k_scan1<<<NS1, 256, 0, stream>>>(deg, loc, bsum, N);
    k_scan2<<<1, 64, 0, stream>>>(bsum, NS1);
    k_scan3<<<nblk, 256, 0, stream>>>(deg, loc, bsum, poffs, pend, cursor, N);
    k_fill<<<(SS / 4 + 255) / 256, 256, 0, stream>>>((int4*)ssrc, N, SS / 4);
    k_scatter<<<eblk, 256, 0, stream>>>(src, dst, cursor, ssrc, E);

    const int gblocks = (N + 63) / 64;
    const int ablocks = (N + 15) / 16;  // 4 nodes/wave, 4 waves/block

    k_mgemm<128><<<gblocks, 256, 0, stream>>>(x, p0h, p0l, as[0], ad[0], xh, als, ald, mvec, N);
    k_agg<<<ablocks, 256, 0, stream>>>(xh, als, ald, mvec, poffs, pend, ssrc, b[0], hbuf, nullptr, nullptr, nullptr, N);
    k_mgemm<64><<<gblocks, 256, 0, stream>>>(hbuf, p1h, p1l, as[1], ad[1], xh, als, ald, mvec, N);
    k_agg<<<ablocks, 256, 0, stream>>>(xh, als, ald, mvec, poffs, pend, ssrc, b[1], hbuf, nullptr, nullptr, nullptr, N);
    k_mgemm<64><<<gblocks, 256, 0, stream>>>(hbuf, p2h, p2l, as[2], ad[2], xh, als, ald, mvec, N);
    k_agg<<<ablocks, 256, 0, stream>>>(xh, als, ald, mvec, poffs, pend, ssrc, b[2], nullptr, outw, outb, (float*)d_out, N);
}

// Round 4
// 435.416 us; speedup vs baseline: 1.3400x; 1.3400x over previous
//
#include <hip/hip_runtime.h>

// GAT node regressor: 3 GAT layers (HID=64, 4 heads x 16) + linear head.
// CSR-by-dst built once per call via bucketed counting sort (LDS-local,
// coalesced writes — the atomic-scatter variant measured 128us/dispatch and
// was reverted), with per-node ranges PADDED to x4 (pad edges -> phantom
// node n: als[n]=-1e30 so pe==0 exactly; xh row n zeroed). Per layer:
//   k_mgemm: xh = h@W on MATRIX CORES via bf16 hi/lo split (fp32 emulation).
//            Wave = 16 nodes x 64 cols, K-step 32, no LDS; W pre-packed by
//            k_wprep. Fused al_s/al_d logits + per-node softmax shift
//            m = lrelu(als+ald) via intra-quad shuffles.
//   k_agg : 4 dst nodes per wave over the padded CSR, SOFTWARE-PIPELINED:
//           chunk i+1's global loads (ssrc -> dependent als[u] gather, ald/m
//           by nid) issue before chunk i's accumulate, hiding the edge-phase
//           latency chain under the gather bursts. Stash (u, pe4)
//           head-transposed in LDS (same-wave RAW, in-order DS unit, no
//           barrier). Accumulate: aligned 4-edge groups, 4-group unroll = 16
//           coalesced 256B row gathers in flight, 2 fmac chains per node.
//           Layer 2 fuses h@out_w via shuffle.

#define NBMAX 512    // max dst buckets (dst>>8); N=100K -> 391
#define SCHUNK 4096  // edges per k_bscatter block
#define BCAP 8192    // per-bucket LDS capacity in k_bfinal (avg 4096+pads)
#define PADSLACK 768 // max padding per bucket = 256 nodes * 3 slots

typedef __attribute__((ext_vector_type(8))) short bf16x8;
typedef __attribute__((ext_vector_type(4))) float f32x4;

__device__ inline unsigned short bf16_rtn(float x) {
    union { float f; unsigned u; } a; a.f = x;
    return (unsigned short)((a.u + 0x7FFFu + ((a.u >> 16) & 1u)) >> 16);
}
__device__ inline float bf16_to_f(unsigned short s) {
    union { unsigned u; float f; } b; b.u = ((unsigned)s) << 16;
    return b.f;
}

// zero bucket hist + init phantom node: als[n]=-1e30 (=> pe 0), xh row n = 0.
__global__ __launch_bounds__(256) void k_init(int* __restrict__ bhist, int nb,
                                              float* __restrict__ als, float* __restrict__ xh, int n) {
    int i = blockIdx.x * 256 + threadIdx.x;
    if (i < nb) bhist[i] = 0;
    int j = i - NBMAX;
    if (j >= 0 && j < 4) als[(size_t)n * 4 + j] = -1e30f;
    int k = i - NBMAX - 4;
    if (k >= 0 && k < 64) xh[(size_t)n * 64 + k] = 0.f;
}

__global__ __launch_bounds__(256) void k_bhist(const int* __restrict__ dst, int* __restrict__ bhist, int e) {
    __shared__ unsigned int h[NBMAX];
    int t = threadIdx.x;
    h[t] = 0;
    h[t + 256] = 0;
    __syncthreads();
    for (int i = blockIdx.x * 256 + t; i < e; i += gridDim.x * 256)
        atomicAdd(&h[dst[i] >> 8], 1u);
    __syncthreads();
    if (h[t]) atomicAdd(&bhist[t], (int)h[t]);
    if (h[t + 256]) atomicAdd(&bhist[t + 256], (int)h[t + 256]);
}

__global__ __launch_bounds__(512) void k_bscan(const int* __restrict__ bhist, int* __restrict__ boffs,
                                               int* __restrict__ bfill, int nb, int e) {
    __shared__ int s[NBMAX];
    int t = threadIdx.x;
    int v = (t < nb) ? bhist[t] : 0;
    s[t] = v;
    __syncthreads();
    for (int o = 1; o < 512; o <<= 1) {
        int add = (t >= o) ? s[t - o] : 0;
        __syncthreads();
        s[t] += add;
        __syncthreads();
    }
    boffs[t] = s[t] - v;  // exclusive
    if (t == 511) boffs[512] = s[511];
    bfill[t] = 0;
}

// Block-local counting sort of a 4096-edge chunk by dst>>8, then streamed
// writes of sorted runs. Packs src (17b) | (dst&255)<<24 into 4B.
__global__ __launch_bounds__(512) void k_bscatter(const int* __restrict__ src, const int* __restrict__ dst,
                                                  const int* __restrict__ boffs, int* __restrict__ bfill,
                                                  unsigned int* __restrict__ edata, int e) {
    __shared__ unsigned int hist[NBMAX];   // counts, then cursor
    __shared__ unsigned int loc[NBMAX];    // local exclusive offsets
    __shared__ int gbase[NBMAX];
    __shared__ unsigned int stmp[NBMAX];
    __shared__ unsigned int sortbuf[SCHUNK];
    __shared__ int posbuf[SCHUNK];
    int t = threadIdx.x;
    int i0 = blockIdx.x * SCHUNK;
    int cnt = min(SCHUNK, e - i0);
    hist[t] = 0;
    __syncthreads();
    for (int j = t; j < cnt; j += 512) atomicAdd(&hist[dst[i0 + j] >> 8], 1u);
    __syncthreads();
    unsigned int v = hist[t];
    stmp[t] = v;
    __syncthreads();
    for (int o = 1; o < 512; o <<= 1) {
        unsigned int add = (t >= o) ? stmp[t - o] : 0;
        __syncthreads();
        stmp[t] += add;
        __syncthreads();
    }
    loc[t] = stmp[t] - v;
    int gb = 0;
    if (v > 0) gb = atomicAdd(&bfill[t], (int)v);  // reserve contiguous run in bucket t
    gbase[t] = boffs[t] + gb - (int)loc[t];
    hist[t] = loc[t];  // cursor
    __syncthreads();
    for (int j = t; j < cnt; j += 512) {
        int d = dst[i0 + j];
        int s = src[i0 + j];
        int b = d >> 8;
        unsigned int p = atomicAdd(&hist[b], 1u);
        sortbuf[p] = (unsigned int)s | ((unsigned int)(d & 255) << 24);
        posbuf[p] = gbase[b] + (int)p;
    }
    __syncthreads();
    for (int j = t; j < cnt; j += 512) edata[posbuf[j]] = sortbuf[j];
}

// One block per bucket: 256-bin counting sort by local dst, ranges padded to
// x4 with phantom-src (= n) entries. Bucket base in padded array:
// pb = boffs[b] + b*PADSLACK (slack bound: 256 nodes x 3). Emits poffs[node]
// (padded start), pend[node] (padded end) and padded ssrc.
__global__ __launch_bounds__(256) void k_bfinal(const unsigned int* __restrict__ edata,
                                                const int* __restrict__ boffs, int* __restrict__ poffs,
                                                int* __restrict__ pend, int* __restrict__ ssrc,
                                                int n, int nb) {
    __shared__ unsigned int hist[256];
    __shared__ unsigned int stmp[256];
    __shared__ unsigned int loc[256];
    __shared__ unsigned int srcbuf[BCAP];
    int b = blockIdx.x;
    int t = threadIdx.x;
    int e0 = boffs[b], e1 = boffs[b + 1];
    int cnt = e1 - e0;
    int pb = e0 + b * PADSLACK;
    hist[t] = 0;
    __syncthreads();
    for (int j = t; j < cnt; j += 256) atomicAdd(&hist[edata[e0 + j] >> 24], 1u);
    __syncthreads();
    unsigned int v = hist[t];
    unsigned int v4 = (v + 3u) & ~3u;  // padded per-node count
    stmp[t] = v4;
    __syncthreads();
    for (int o = 1; o < 256; o <<= 1) {
        unsigned int add = (t >= o) ? stmp[t - o] : 0;
        __syncthreads();
        stmp[t] += add;
        __syncthreads();
    }
    loc[t] = stmp[t] - v4;  // padded exclusive offset
    int ptot = (int)stmp[255];
    int node = b * 256 + t;
    if (node < n) {
        poffs[node] = pb + (int)loc[t];
        pend[node] = pb + (int)(loc[t] + v4);
    }
    hist[t] = loc[t];  // cursor
    __syncthreads();
    if (cnt + PADSLACK <= BCAP) {
        for (int j = t; j < cnt; j += 256) {
            unsigned int p = edata[e0 + j];
            unsigned int pos = atomicAdd(&hist[p >> 24], 1u);
            srcbuf[pos] = p & 0xFFFFFFu;
        }
        for (unsigned int k = v; k < v4; ++k) srcbuf[loc[t] + k] = (unsigned int)n;  // pads
        __syncthreads();
        for (int j = t; j < ptot; j += 256) ssrc[pb + j] = (int)srcbuf[j];
    } else {  // safety fallback (never hit for Poisson(4096) buckets)
        for (int j = t; j < cnt; j += 256) {
            unsigned int p = edata[e0 + j];
            unsigned int pos = atomicAdd(&hist[p >> 24], 1u);
            ssrc[pb + (int)pos] = (int)(p & 0xFFFFFFu);
        }
        for (unsigned int k = v; k < v4; ++k) ssrc[pb + (int)(loc[t] + k)] = n;
    }
}

// Pack all three layers' W (fp32 [D][64]) into MFMA B-fragment order, hi/lo
// bf16: pack[((ko*64)+n)*8 + j] = bf16(W[ko*8+j][n]). One thread per (ko,n).
__global__ __launch_bounds__(256) void k_wprep(const float* __restrict__ w0, const float* __restrict__ w1,
                                               const float* __restrict__ w2,
                                               unsigned short* __restrict__ p0h, unsigned short* __restrict__ p0l,
                                               unsigned short* __restrict__ p1h, unsigned short* __restrict__ p1l,
                                               unsigned short* __restrict__ p2h, unsigned short* __restrict__ p2l) {
    int g = blockIdx.x * 256 + threadIdx.x;
    const float* W;
    unsigned short *ph, *pl;
    int idx;
    if (g < 1024) { W = w0; ph = p0h; pl = p0l; idx = g; }          // D=128: ko 0..15
    else if (g < 1536) { W = w1; ph = p1h; pl = p1l; idx = g - 1024; }  // D=64: ko 0..7
    else if (g < 2048) { W = w2; ph = p2h; pl = p2l; idx = g - 1536; }
    else return;
    int ko = idx >> 6, nn = idx & 63;
#pragma unroll
    for (int j = 0; j < 8; ++j) {
        float w = W[(size_t)(ko * 8 + j) * 64 + nn];
        unsigned short hb = bf16_rtn(w);
        ph[(size_t)idx * 8 + j] = hb;
        pl[(size_t)idx * 8 + j] = bf16_rtn(w - bf16_to_f(hb));
    }
}

// xh = h @ W via MFMA, fused attention logits + per-node softmax shift m.
template <int D_IN>
__global__ __launch_bounds__(256) void k_mgemm(const float* __restrict__ h,
                                               const unsigned short* __restrict__ wph,
                                               const unsigned short* __restrict__ wpl,
                                               const float* __restrict__ asrc, const float* __restrict__ adst,
                                               float* __restrict__ xh, float* __restrict__ als,
                                               float* __restrict__ ald, float* __restrict__ mvec, int n) {
    int t = threadIdx.x;
    int wv = t >> 6, lane = t & 63;
    int quad = lane >> 4, l16 = lane & 15;
    int m0 = blockIdx.x * 64 + wv * 16;
    int node_a = m0 + l16;
    int mm = min(node_a, n - 1);
    const float* hrow = h + (size_t)mm * D_IN + quad * 8;

    f32x4 acc[4];
#pragma unroll
    for (int i = 0; i < 4; ++i) acc[i] = (f32x4){0.f, 0.f, 0.f, 0.f};

    constexpr int KSTEPS = D_IN / 32;
#pragma unroll
    for (int s = 0; s < KSTEPS; ++s) {
        float4 a0 = *(const float4*)(hrow + s * 32);
        float4 a1 = *(const float4*)(hrow + s * 32 + 4);
        float av[8] = {a0.x, a0.y, a0.z, a0.w, a1.x, a1.y, a1.z, a1.w};
        bf16x8 ahi, alo;
#pragma unroll
        for (int j = 0; j < 8; ++j) {
            unsigned short hb = bf16_rtn(av[j]);
            ahi[j] = (short)hb;
            alo[j] = (short)bf16_rtn(av[j] - bf16_to_f(hb));
        }
        const unsigned short* bbase = wph + ((size_t)((s * 4 + quad) * 64 + l16)) * 8;
        const unsigned short* bbasel = wpl + ((size_t)((s * 4 + quad) * 64 + l16)) * 8;
#pragma unroll
        for (int nt = 0; nt < 4; ++nt) {
            bf16x8 bhi = *(const bf16x8*)(bbase + (size_t)nt * 16 * 8);
            bf16x8 blo = *(const bf16x8*)(bbasel + (size_t)nt * 16 * 8);
            acc[nt] = __builtin_amdgcn_mfma_f32_16x16x32_bf16(ahi, bhi, acc[nt], 0, 0, 0);
            acc[nt] = __builtin_amdgcn_mfma_f32_16x16x32_bf16(ahi, blo, acc[nt], 0, 0, 0);
            acc[nt] = __builtin_amdgcn_mfma_f32_16x16x32_bf16(alo, bhi, acc[nt], 0, 0, 0);
        }
    }
    // epilogue: store xh + fused logits (head == N-tile: 16 cols/head)
#pragma unroll
    for (int nt = 0; nt < 4; ++nt) {
        float as_l = asrc[nt * 16 + l16];
        float ad_l = adst[nt * 16 + l16];
#pragma unroll
        for (int r = 0; r < 4; ++r) {
            int node = m0 + quad * 4 + r;
            float c = acc[nt][r];
            if (node < n) xh[(size_t)node * 64 + nt * 16 + l16] = c;
            float ps = c * as_l, pd = c * ad_l;
            ps += __shfl_xor(ps, 1, 64); pd += __shfl_xor(pd, 1, 64);
            ps += __shfl_xor(ps, 2, 64); pd += __shfl_xor(pd, 2, 64);
            ps += __shfl_xor(ps, 4, 64); pd += __shfl_xor(pd, 4, 64);
            ps += __shfl_xor(ps, 8, 64); pd += __shfl_xor(pd, 8, 64);
            if (l16 == 0 && node < n) {
                als[node * 4 + nt] = ps;
                ald[node * 4 + nt] = pd;
                float sm = ps + pd;
                mvec[node * 4 + nt] = sm >= 0.f ? sm : 0.2f * sm;
            }
        }
    }
}

__device__ inline float4 lrelu4(float4 v) {
    float4 r;
    r.x = v.x >= 0.f ? v.x : 0.2f * v.x;
    r.y = v.y >= 0.f ? v.y : 0.2f * v.y;
    r.z = v.z >= 0.f ? v.z : 0.2f * v.z;
    r.w = v.w >= 0.f ? v.w : 0.2f * v.w;
    return r;
}

// Aligned accumulate over [LO,HI) within chunk starting at s0; two fmac
// chains per node (ACCA/ACCB) to halve dependency stalls.
#define ACCUM(LO, HI, ACCA, ACCB, ZS)                                           \
    {                                                                           \
        int g_ = ((LO) - s0) >> 2, gb_ = ((HI) - s0) >> 2;                      \
        for (; g_ + 4 <= gb_; g_ += 4) {                                        \
            int4 uu0 = *(const int4*)&ub[g_ * 4];                               \
            int4 uu1 = *(const int4*)&ub[g_ * 4 + 4];                           \
            int4 uu2 = *(const int4*)&ub[g_ * 4 + 8];                           \
            int4 uu3 = *(const int4*)&ub[g_ * 4 + 12];                          \
            float4 pp0 = *(const float4*)&per[g_ * 4];                          \
            float4 pp1 = *(const float4*)&per[g_ * 4 + 4];                      \
            float4 pp2 = *(const float4*)&per[g_ * 4 + 8];                      \
            float4 pp3 = *(const float4*)&per[g_ * 4 + 12];                     \
            float x0 = *(const float*)(xl + (size_t)(unsigned)uu0.x);           \
            float x1 = *(const float*)(xl + (size_t)(unsigned)uu0.y);           \
            float x2 = *(const float*)(xl + (size_t)(unsigned)uu0.z);           \
            float x3 = *(const float*)(xl + (size_t)(unsigned)uu0.w);           \
            float x4 = *(const float*)(xl + (size_t)(unsigned)uu1.x);           \
            float x5 = *(const float*)(xl + (size_t)(unsigned)uu1.y);           \
            float x6 = *(const float*)(xl + (size_t)(unsigned)uu1.z);           \
            float x7 = *(const float*)(xl + (size_t)(unsigned)uu1.w);           \
            float x8 = *(const float*)(xl + (size_t)(unsigned)uu2.x);           \
            float x9 = *(const float*)(xl + (size_t)(unsigned)uu2.y);           \
            float xa = *(const float*)(xl + (size_t)(unsigned)uu2.z);           \
            float xb = *(const float*)(xl + (size_t)(unsigned)uu2.w);           \
            float xc = *(const float*)(xl + (size_t)(unsigned)uu3.x);           \
            float xd = *(const float*)(xl + (size_t)(unsigned)uu3.y);           \
            float xe = *(const float*)(xl + (size_t)(unsigned)uu3.z);           \
            float xf = *(const float*)(xl + (size_t)(unsigned)uu3.w);           \
            ZS += pp0.x + pp0.y + pp0.z + pp0.w;                                \
            ZS += pp1.x + pp1.y + pp1.z + pp1.w;                                \
            ZS += pp2.x + pp2.y + pp2.z + pp2.w;                                \
            ZS += pp3.x + pp3.y + pp3.z + pp3.w;                                \
            ACCA += pp0.x * x0; ACCB += pp0.y * x1;                             \
            ACCA += pp0.z * x2; ACCB += pp0.w * x3;                             \
            ACCA += pp1.x * x4; ACCB += pp1.y * x5;                             \
            ACCA += pp1.z * x6; ACCB += pp1.w * x7;                             \
            ACCA += pp2.x * x8; ACCB += pp2.y * x9;                             \
            ACCA += pp2.z * xa; ACCB += pp2.w * xb;                             \
            ACCA += pp3.x * xc; ACCB += pp3.y * xd;                             \
            ACCA += pp3.z * xe; ACCB += pp3.w * xf;                             \
        }                                                                       \
        for (; g_ < gb_; ++g_) {                                                \
            int4 uu = *(const int4*)&ub[g_ * 4];                                \
            float4 pp = *(const float4*)&per[g_ * 4];                           \
            float x0 = *(const float*)(xl + (size_t)(unsigned)uu.x);            \
            float x1 = *(const float*)(xl + (size_t)(unsigned)uu.y);            \
            float x2 = *(const float*)(xl + (size_t)(unsigned)uu.z);            \
            float x3 = *(const float*)(xl + (size_t)(unsigned)uu.w);            \
            ZS += pp.x + pp.y + pp.z + pp.w;                                    \
            ACCA += pp.x * x0; ACCB += pp.y * x1;                               \
            ACCA += pp.z * x2; ACCB += pp.w * x3;                               \
        }                                                                       \
    }

__global__ __launch_bounds__(256) void k_agg(const float* __restrict__ xh,
                                             const float* __restrict__ als, const float* __restrict__ ald,
                                             const float* __restrict__ mvec,
                                             const int* __restrict__ poffs, const int* __restrict__ pend,
                                             const int* __restrict__ ssrc,
                                             const float* __restrict__ bias, float* __restrict__ hout,
                                             const float* __restrict__ outw, const float* __restrict__ outb,
                                             float* __restrict__ fout, int n) {
    __shared__ int s_u[4][64];
    __shared__ float s_pe[4][4][64];  // [wslot][head][edge]
    int wslot = threadIdx.x >> 6;
    int lane = threadIdx.x & 63;
    int w = (blockIdx.x * 256 + threadIdx.x) >> 6;
    int v0 = w << 2;
    if (v0 >= n) return;
    int head = lane >> 4;
    int* ub = s_u[wslot];
    float* per = s_pe[wslot][head];      // read row for my head
    float* pew = &s_pe[wslot][0][lane];  // write base, stride 64 per head

    int vlast = n - 1;
    int last = min(v0 + 3, vlast);
    int4 rr = *(const int4*)(poffs + v0);
    int e3 = pend[last];
    int r0 = rr.x;
    int r1 = (v0 + 1 <= last) ? rr.y : e3;
    int r2 = (v0 + 2 <= last) ? rr.z : e3;
    int r3 = (v0 + 3 <= last) ? rr.w : e3;

    const char* xl = (const char*)(xh + lane);  // lane column folded into base
    // self edges (pe = 1); issued up-front, all independent
    float acc0a = *(const float*)(xl + ((size_t)(unsigned)v0 << 8));
    float acc1a = *(const float*)(xl + ((size_t)(unsigned)min(v0 + 1, vlast) << 8));
    float acc2a = *(const float*)(xl + ((size_t)(unsigned)min(v0 + 2, vlast) << 8));
    float acc3a = *(const float*)(xl + ((size_t)(unsigned)min(v0 + 3, vlast) << 8));
    float acc0b = 0.f, acc1b = 0.f, acc2b = 0.f, acc3b = 0.f;
    float zs0 = 0.f, zs1 = 0.f, zs2 = 0.f, zs3 = 0.f;

    // prefetch chunk 0 (ssrc -> dependent als gather; ald/m by nid)
    int s0 = r0;
    int u_n = n;
    if (s0 < e3) {
        if (lane < e3 - s0) u_n = ssrc[s0 + lane];
    }
    float4 alu_n = *(const float4*)(als + 4 * (size_t)u_n);
    int e_n = s0 + lane;
    int nid_n = min(v0 + (e_n >= r1) + (e_n >= r2) + (e_n >= r3), vlast);
    float4 ald_n = *(const float4*)(ald + 4 * (size_t)nid_n);
    float4 m_n = *(const float4*)(mvec + 4 * (size_t)nid_n);

    while (s0 < e3) {
        int cnt = min(64, e3 - s0);
        // pe for current chunk from prefetched values
        float4 e4 = lrelu4(make_float4(alu_n.x + ald_n.x, alu_n.y + ald_n.y,
                                       alu_n.z + ald_n.z, alu_n.w + ald_n.w));
        float4 pe;
        pe.x = __expf(e4.x - m_n.x);
        pe.y = __expf(e4.y - m_n.y);
        pe.z = __expf(e4.z - m_n.z);
        pe.w = __expf(e4.w - m_n.w);
        ub[lane] = u_n << 8;  // row byte offset; pads point at phantom n
        pew[0] = pe.x;        // transposed stash: bank stride 64 -> 2-way, free
        pew[64] = pe.y;
        pew[128] = pe.z;
        pew[192] = pe.w;
        // issue next chunk's loads before the long accumulate phase
        int s1 = s0 + 64;
        if (s1 < e3) {
            u_n = n;
            if (lane < e3 - s1) u_n = ssrc[s1 + lane];
            alu_n = *(const float4*)(als + 4 * (size_t)u_n);
            int e1 = s1 + lane;
            int nid1 = min(v0 + (e1 >= r1) + (e1 >= r2) + (e1 >= r3), vlast);
            ald_n = *(const float4*)(ald + 4 * (size_t)nid1);
            m_n = *(const float4*)(mvec + 4 * (size_t)nid1);
        }
        // same-wave LDS RAW (in-order DS unit), no barrier needed
        int lim = s0 + cnt;
        int hi0 = min(r1, lim);
        int lo1 = max(r1, s0), hi1 = min(r2, lim);
        int lo2 = max(r2, s0), hi2 = min(r3, lim);
        int lo3 = max(r3, s0);
        ACCUM(s0, hi0, acc0a, acc0b, zs0);
        ACCUM(lo1, hi1, acc1a, acc1b, zs1);
        ACCUM(lo2, hi2, acc2a, acc2b, zs2);
        ACCUM(lo3, lim, acc3a, acc3b, zs3);
        s0 = s1;
    }

    float bl = bias[lane];
    float o0 = fmaxf((acc0a + acc0b) / (1.f + zs0 + 1e-16f) + bl, 0.f);
    float o1 = fmaxf((acc1a + acc1b) / (1.f + zs1 + 1e-16f) + bl, 0.f);
    float o2 = fmaxf((acc2a + acc2b) / (1.f + zs2 + 1e-16f) + bl, 0.f);
    float o3 = fmaxf((acc3a + acc3b) / (1.f + zs3 + 1e-16f) + bl, 0.f);
    if (outw) {
        float ow = outw[lane];
        float ob = outb[0];
        float t0 = o0 * ow, t1 = o1 * ow, t2 = o2 * ow, t3 = o3 * ow;
#pragma unroll
        for (int d = 32; d; d >>= 1) {
            t0 += __shfl_down(t0, d, 64);
            t1 += __shfl_down(t1, d, 64);
            t2 += __shfl_down(t2, d, 64);
            t3 += __shfl_down(t3, d, 64);
        }
        if (lane == 0) {
            fout[v0] = t0 + ob;
            if (v0 + 1 < n) fout[v0 + 1] = t1 + ob;
            if (v0 + 2 < n) fout[v0 + 2] = t2 + ob;
            if (v0 + 3 < n) fout[v0 + 3] = t3 + ob;
        }
    } else {
        hout[((size_t)v0 << 6) + lane] = o0;
        if (v0 + 1 < n) hout[((size_t)(v0 + 1) << 6) + lane] = o1;
        if (v0 + 2 < n) hout[((size_t)(v0 + 2) << 6) + lane] = o2;
        if (v0 + 3 < n) hout[((size_t)(v0 + 3) << 6) + lane] = o3;
    }
}

extern "C" void kernel_launch(void* const* d_in, const int* in_sizes, int n_in,
                              void* d_out, int out_size, void* d_ws, size_t ws_size,
                              hipStream_t stream) {
    const float* x = (const float*)d_in[0];
    const int* ei = (const int*)d_in[1];
    const float* w[3] = {(const float*)d_in[2], (const float*)d_in[6], (const float*)d_in[10]};
    const float* as[3] = {(const float*)d_in[3], (const float*)d_in[7], (const float*)d_in[11]};
    const float* ad[3] = {(const float*)d_in[4], (const float*)d_in[8], (const float*)d_in[12]};
    const float* b[3] = {(const float*)d_in[5], (const float*)d_in[9], (const float*)d_in[13]};
    const float* outw = (const float*)d_in[14];
    const float* outb = (const float*)d_in[15];

    const int N = in_sizes[0] / 128;
    const int E = in_sizes[1] / 2;
    const int* src = ei;
    const int* dst = ei + E;
    const int NB = (N + 255) / 256;  // 391 <= NBMAX

    char* ws = (char*)d_ws;
    auto alloc = [&](size_t bytes) -> void* {
        void* p = (void*)ws;
        ws += (bytes + 255) & ~(size_t)255;
        return p;
    };
    int* bhist = (int*)alloc(NBMAX * 4);
    int* boffs = (int*)alloc((NBMAX + 1) * 4);
    int* bfill = (int*)alloc(NBMAX * 4);
    int* poffs = (int*)alloc((size_t)(N + 8) * 4);
    int* pend = (int*)alloc((size_t)N * 4);
    int* ssrc = (int*)alloc((size_t)(E + NBMAX * PADSLACK + 256) * 4);
    float* xh = (float*)alloc((size_t)(N + 1) * 64 * 4);  // +1: phantom zero row
    float* hbuf = (float*)alloc((size_t)N * 64 * 4);
    float* als = (float*)alloc((size_t)(N + 1) * 4 * 4);  // +1: phantom -1e30
    float* ald = (float*)alloc((size_t)N * 4 * 4);
    float* mvec = (float*)alloc((size_t)N * 4 * 4);
    unsigned short* p0h = (unsigned short*)alloc(8192 * 2);
    unsigned short* p0l = (unsigned short*)alloc(8192 * 2);
    unsigned short* p1h = (unsigned short*)alloc(4096 * 2);
    unsigned short* p1l = (unsigned short*)alloc(4096 * 2);
    unsigned short* p2h = (unsigned short*)alloc(4096 * 2);
    unsigned short* p2l = (unsigned short*)alloc(4096 * 2);
    // edata (E*4B = 6.4MB) aliases xh rows [0, E/64): dead before k_mgemm
    // writes xh; phantom row n (byte offset N*256 = 25.6MB) is untouched.
    unsigned int* edata = (unsigned int*)xh;

    k_wprep<<<8, 256, 0, stream>>>(w[0], w[1], w[2], p0h, p0l, p1h, p1l, p2h, p2l);
    k_init<<<3, 256, 0, stream>>>(bhist, NBMAX, als, xh, N);
    k_bhist<<<256, 256, 0, stream>>>(dst, bhist, E);
    k_bscan<<<1, 512, 0, stream>>>(bhist, boffs, bfill, NB, E);
    k_bscatter<<<(E + SCHUNK - 1) / SCHUNK, 512, 0, stream>>>(src, dst, boffs, bfill, edata, E);
    k_bfinal<<<NB, 256, 0, stream>>>(edata, boffs, poffs, pend, ssrc, N, NB);

    const int gblocks = (N + 63) / 64;
    const int ablocks = (N + 15) / 16;  // 4 nodes/wave, 4 waves/block

    k_mgemm<128><<<gblocks, 256, 0, stream>>>(x, p0h, p0l, as[0], ad[0], xh, als, ald, mvec, N);
    k_agg<<<ablocks, 256, 0, stream>>>(xh, als, ald, mvec, poffs, pend, ssrc, b[0], hbuf, nullptr, nullptr, nullptr, N);
    k_mgemm<64><<<gblocks, 256, 0, stream>>>(hbuf, p1h, p1l, as[1], ad[1], xh, als, ald, mvec, N);
    k_agg<<<ablocks, 256, 0, stream>>>(xh, als, ald, mvec, poffs, pend, ssrc, b[1], hbuf, nullptr, nullptr, nullptr, N);
    k_mgemm<64><<<gblocks, 256, 0, stream>>>(hbuf, p2h, p2l, as[2], ad[2], xh, als, ald, mvec, N);
    k_agg<<<ablocks, 256, 0, stream>>>(xh, als, ald, mvec, poffs, pend, ssrc, b[2], nullptr, outw, outb, (float*)d_out, N);
}

// Round 5
// 426.599 us; speedup vs baseline: 1.3677x; 1.0207x over previous
//
#include <hip/hip_runtime.h>

// GAT node regressor: 3 GAT layers (HID=64, 4 heads x 16) + linear head.
// CSR-by-dst built once per call via bucketed counting sort, per-node ranges
// PADDED to x4 (pad edges -> phantom node n: als[n]=-1e30 so pe==0; xh row n
// zeroed). k_agg is BW-bound on random 256B xh gathers (measured 3.6TB/s
// effective, R4 pipeline A/B null) — left untouched. This round overlaps the
// independent mgemm<128> with the CSR build via role-split merged kernels:
//   k_mix1 = bscatter(391 blk) || mgemm<128> first half (391 blk, 8 waves)
//   k_mix2 = bfinal(391 blk)  || mgemm<128> second half
// (each CSR role alone is 1.53 block-rounds on 256 CUs -> ~35% tail idle;
// mgemm blocks fill the gap). edata NO LONGER aliases xh (mgemm writes xh
// concurrently with edata's live range) — own 6.4MB slab.

#define NBMAX 512    // max dst buckets (dst>>8); N=100K -> 391
#define SCHUNK 4096  // edges per bscatter block
#define BCAP 8192    // per-bucket LDS capacity in bfinal (avg 4096+pads)
#define PADSLACK 768 // max padding per bucket = 256 nodes * 3 slots

typedef __attribute__((ext_vector_type(8))) short bf16x8;
typedef __attribute__((ext_vector_type(4))) float f32x4;

__device__ inline unsigned short bf16_rtn(float x) {
    union { float f; unsigned u; } a; a.f = x;
    return (unsigned short)((a.u + 0x7FFFu + ((a.u >> 16) & 1u)) >> 16);
}
__device__ inline float bf16_to_f(unsigned short s) {
    union { unsigned u; float f; } b; b.u = ((unsigned)s) << 16;
    return b.f;
}

// ---- fused W-prep + init (9 blocks: 0-7 wprep, 8 init) ----
__global__ __launch_bounds__(256) void k_prep(const float* __restrict__ w0, const float* __restrict__ w1,
                                              const float* __restrict__ w2,
                                              unsigned short* __restrict__ p0h, unsigned short* __restrict__ p0l,
                                              unsigned short* __restrict__ p1h, unsigned short* __restrict__ p1l,
                                              unsigned short* __restrict__ p2h, unsigned short* __restrict__ p2l,
                                              int* __restrict__ bhist, float* __restrict__ als,
                                              float* __restrict__ xh, int n) {
    int bid = blockIdx.x, t = threadIdx.x;
    if (bid == 8) {  // init: zero bucket hist + phantom node
        bhist[t] = 0;
        bhist[t + 256] = 0;
        if (t < 4) als[(size_t)n * 4 + t] = -1e30f;
        if (t < 64) xh[(size_t)n * 64 + t] = 0.f;
        return;
    }
    int g = bid * 256 + t;
    const float* W;
    unsigned short *ph, *pl;
    int idx;
    if (g < 1024) { W = w0; ph = p0h; pl = p0l; idx = g; }          // D=128: ko 0..15
    else if (g < 1536) { W = w1; ph = p1h; pl = p1l; idx = g - 1024; }  // D=64: ko 0..7
    else if (g < 2048) { W = w2; ph = p2h; pl = p2l; idx = g - 1536; }
    else return;
    int ko = idx >> 6, nn = idx & 63;
#pragma unroll
    for (int j = 0; j < 8; ++j) {
        float w = W[(size_t)(ko * 8 + j) * 64 + nn];
        unsigned short hb = bf16_rtn(w);
        ph[(size_t)idx * 8 + j] = hb;
        pl[(size_t)idx * 8 + j] = bf16_rtn(w - bf16_to_f(hb));
    }
}

__global__ __launch_bounds__(256) void k_bhist(const int* __restrict__ dst, int* __restrict__ bhist, int e) {
    __shared__ unsigned int h[NBMAX];
    int t = threadIdx.x;
    h[t] = 0;
    h[t + 256] = 0;
    __syncthreads();
    for (int i = blockIdx.x * 256 + t; i < e; i += gridDim.x * 256)
        atomicAdd(&h[dst[i] >> 8], 1u);
    __syncthreads();
    if (h[t]) atomicAdd(&bhist[t], (int)h[t]);
    if (h[t + 256]) atomicAdd(&bhist[t + 256], (int)h[t + 256]);
}

__global__ __launch_bounds__(512) void k_bscan(const int* __restrict__ bhist, int* __restrict__ boffs,
                                               int* __restrict__ bfill, int nb, int e) {
    __shared__ int s[NBMAX];
    int t = threadIdx.x;
    int v = (t < nb) ? bhist[t] : 0;
    s[t] = v;
    __syncthreads();
    for (int o = 1; o < 512; o <<= 1) {
        int add = (t >= o) ? s[t - o] : 0;
        __syncthreads();
        s[t] += add;
        __syncthreads();
    }
    boffs[t] = s[t] - v;  // exclusive
    if (t == 511) boffs[512] = s[511];
    bfill[t] = 0;
}

// ---- mgemm wave body: 16 nodes x 64 cols, fused logits + softmax shift ----
template <int D_IN>
__device__ __forceinline__ void mgemm_wave(const float* __restrict__ h,
                                           const unsigned short* __restrict__ wph,
                                           const unsigned short* __restrict__ wpl,
                                           const float* __restrict__ asrc, const float* __restrict__ adst,
                                           float* __restrict__ xh, float* __restrict__ als,
                                           float* __restrict__ ald, float* __restrict__ mvec,
                                           int m0, int lane, int n) {
    int quad = lane >> 4, l16 = lane & 15;
    int node_a = m0 + l16;
    int mm = min(node_a, n - 1);
    const float* hrow = h + (size_t)mm * D_IN + quad * 8;

    f32x4 acc[4];
#pragma unroll
    for (int i = 0; i < 4; ++i) acc[i] = (f32x4){0.f, 0.f, 0.f, 0.f};

    constexpr int KSTEPS = D_IN / 32;
#pragma unroll
    for (int s = 0; s < KSTEPS; ++s) {
        float4 a0 = *(const float4*)(hrow + s * 32);
        float4 a1 = *(const float4*)(hrow + s * 32 + 4);
        float av[8] = {a0.x, a0.y, a0.z, a0.w, a1.x, a1.y, a1.z, a1.w};
        bf16x8 ahi, alo;
#pragma unroll
        for (int j = 0; j < 8; ++j) {
            unsigned short hb = bf16_rtn(av[j]);
            ahi[j] = (short)hb;
            alo[j] = (short)bf16_rtn(av[j] - bf16_to_f(hb));
        }
        const unsigned short* bbase = wph + ((size_t)((s * 4 + quad) * 64 + l16)) * 8;
        const unsigned short* bbasel = wpl + ((size_t)((s * 4 + quad) * 64 + l16)) * 8;
#pragma unroll
        for (int nt = 0; nt < 4; ++nt) {
            bf16x8 bhi = *(const bf16x8*)(bbase + (size_t)nt * 16 * 8);
            bf16x8 blo = *(const bf16x8*)(bbasel + (size_t)nt * 16 * 8);
            acc[nt] = __builtin_amdgcn_mfma_f32_16x16x32_bf16(ahi, bhi, acc[nt], 0, 0, 0);
            acc[nt] = __builtin_amdgcn_mfma_f32_16x16x32_bf16(ahi, blo, acc[nt], 0, 0, 0);
            acc[nt] = __builtin_amdgcn_mfma_f32_16x16x32_bf16(alo, bhi, acc[nt], 0, 0, 0);
        }
    }
#pragma unroll
    for (int nt = 0; nt < 4; ++nt) {
        float as_l = asrc[nt * 16 + l16];
        float ad_l = adst[nt * 16 + l16];
#pragma unroll
        for (int r = 0; r < 4; ++r) {
            int node = m0 + quad * 4 + r;
            float c = acc[nt][r];
            if (node < n) xh[(size_t)node * 64 + nt * 16 + l16] = c;
            float ps = c * as_l, pd = c * ad_l;
            ps += __shfl_xor(ps, 1, 64); pd += __shfl_xor(pd, 1, 64);
            ps += __shfl_xor(ps, 2, 64); pd += __shfl_xor(pd, 2, 64);
            ps += __shfl_xor(ps, 4, 64); pd += __shfl_xor(pd, 4, 64);
            ps += __shfl_xor(ps, 8, 64); pd += __shfl_xor(pd, 8, 64);
            if (l16 == 0 && node < n) {
                als[node * 4 + nt] = ps;
                ald[node * 4 + nt] = pd;
                float sm = ps + pd;
                mvec[node * 4 + nt] = sm >= 0.f ? sm : 0.2f * sm;
            }
        }
    }
}

// Standalone mgemm for layers 1-2 (D=64): 4 waves x 16 nodes.
template <int D_IN>
__global__ __launch_bounds__(256) void k_mgemm(const float* __restrict__ h,
                                               const unsigned short* __restrict__ wph,
                                               const unsigned short* __restrict__ wpl,
                                               const float* __restrict__ asrc, const float* __restrict__ adst,
                                               float* __restrict__ xh, float* __restrict__ als,
                                               float* __restrict__ ald, float* __restrict__ mvec, int n) {
    int t = threadIdx.x;
    int m0 = blockIdx.x * 64 + (t >> 6) * 16;
    mgemm_wave<D_IN>(h, wph, wpl, asrc, adst, xh, als, ald, mvec, m0, t & 63, n);
}

// ---- k_mix1: bscatter (blocks [0,sb)) || mgemm<128> half 1 (8 waves/blk) ----
__global__ __launch_bounds__(512) void k_mix1(const int* __restrict__ src, const int* __restrict__ dst,
                                              const int* __restrict__ boffs, int* __restrict__ bfill,
                                              unsigned int* __restrict__ edata, int e, int sb,
                                              const float* __restrict__ x,
                                              const unsigned short* __restrict__ p0h,
                                              const unsigned short* __restrict__ p0l,
                                              const float* __restrict__ asrc, const float* __restrict__ adst,
                                              float* __restrict__ xh, float* __restrict__ als,
                                              float* __restrict__ ald, float* __restrict__ mvec, int n) {
    __shared__ unsigned int hist[NBMAX];
    __shared__ unsigned int loc[NBMAX];
    __shared__ int gbase[NBMAX];
    __shared__ unsigned int stmp[NBMAX];
    __shared__ unsigned int sortbuf[SCHUNK];
    __shared__ int posbuf[SCHUNK];
    int t = threadIdx.x;
    if (blockIdx.x >= sb) {  // mgemm role: nodes [mblk*128, mblk*128+128)
        int mblk = blockIdx.x - sb;
        int m0 = mblk * 128 + (t >> 6) * 16;
        mgemm_wave<128>(x, p0h, p0l, asrc, adst, xh, als, ald, mvec, m0, t & 63, n);
        return;
    }
    // bscatter role: block-local counting sort of a 4096-edge chunk by dst>>8
    int i0 = blockIdx.x * SCHUNK;
    int cnt = min(SCHUNK, e - i0);
    hist[t] = 0;
    __syncthreads();
    for (int j = t; j < cnt; j += 512) atomicAdd(&hist[dst[i0 + j] >> 8], 1u);
    __syncthreads();
    unsigned int v = hist[t];
    stmp[t] = v;
    __syncthreads();
    for (int o = 1; o < 512; o <<= 1) {
        unsigned int add = (t >= o) ? stmp[t - o] : 0;
        __syncthreads();
        stmp[t] += add;
        __syncthreads();
    }
    loc[t] = stmp[t] - v;
    int gb = 0;
    if (v > 0) gb = atomicAdd(&bfill[t], (int)v);  // reserve contiguous run in bucket t
    gbase[t] = boffs[t] + gb - (int)loc[t];
    hist[t] = loc[t];  // cursor
    __syncthreads();
    for (int j = t; j < cnt; j += 512) {
        int d = dst[i0 + j];
        int s = src[i0 + j];
        int b = d >> 8;
        unsigned int p = atomicAdd(&hist[b], 1u);
        sortbuf[p] = (unsigned int)s | ((unsigned int)(d & 255) << 24);
        posbuf[p] = gbase[b] + (int)p;
    }
    __syncthreads();
    for (int j = t; j < cnt; j += 512) edata[posbuf[j]] = sortbuf[j];
}

// ---- k_mix2: bfinal (blocks [0,nb)) || mgemm<128> half 2 ----
__global__ __launch_bounds__(512) void k_mix2(const unsigned int* __restrict__ edata,
                                              const int* __restrict__ boffs, int* __restrict__ poffs,
                                              int* __restrict__ pend, int* __restrict__ ssrc,
                                              int n, int nb, int mg1,
                                              const float* __restrict__ x,
                                              const unsigned short* __restrict__ p0h,
                                              const unsigned short* __restrict__ p0l,
                                              const float* __restrict__ asrc, const float* __restrict__ adst,
                                              float* __restrict__ xh, float* __restrict__ als,
                                              float* __restrict__ ald, float* __restrict__ mvec) {
    __shared__ unsigned int hist[256];
    __shared__ unsigned int stmp[256];
    __shared__ unsigned int loc2[256];
    __shared__ unsigned int srcbuf[BCAP];
    int t = threadIdx.x;
    if (blockIdx.x >= nb) {  // mgemm role: second half of nodes
        int mblk = mg1 + (blockIdx.x - nb);
        int m0 = mblk * 128 + (t >> 6) * 16;
        mgemm_wave<128>(x, p0h, p0l, asrc, adst, xh, als, ald, mvec, m0, t & 63, n);
        return;
    }
    // bfinal role: 256-bin counting sort by local dst, padded to x4
    int b = blockIdx.x;
    int e0 = boffs[b], e1 = boffs[b + 1];
    int cnt = e1 - e0;
    int pb = e0 + b * PADSLACK;
    if (t < 256) hist[t] = 0;
    __syncthreads();
    for (int j = t; j < cnt; j += 512) atomicAdd(&hist[edata[e0 + j] >> 24], 1u);
    __syncthreads();
    unsigned int v = 0, v4 = 0;
    if (t < 256) {
        v = hist[t];
        v4 = (v + 3u) & ~3u;
        stmp[t] = v4;
    }
    __syncthreads();
    for (int o = 1; o < 256; o <<= 1) {
        unsigned int add = 0;
        if (t < 256 && t >= o) add = stmp[t - o];
        __syncthreads();
        if (t < 256) stmp[t] += add;
        __syncthreads();
    }
    int ptot = (int)stmp[255];
    if (t < 256) {
        loc2[t] = stmp[t] - v4;  // padded exclusive offset
        int node = b * 256 + t;
        if (node < n) {
            poffs[node] = pb + (int)loc2[t];
            pend[node] = pb + (int)(loc2[t] + v4);
        }
        hist[t] = loc2[t];  // cursor
    }
    __syncthreads();
    if (cnt + PADSLACK <= BCAP) {
        for (int j = t; j < cnt; j += 512) {
            unsigned int p = edata[e0 + j];
            unsigned int pos = atomicAdd(&hist[p >> 24], 1u);
            srcbuf[pos] = p & 0xFFFFFFu;
        }
        if (t < 256)
            for (unsigned int k = v; k < v4; ++k) srcbuf[loc2[t] + k] = (unsigned int)n;  // pads
        __syncthreads();
        for (int j = t; j < ptot; j += 512) ssrc[pb + j] = (int)srcbuf[j];
    } else {  // safety fallback (never hit for Poisson(4096) buckets)
        for (int j = t; j < cnt; j += 512) {
            unsigned int p = edata[e0 + j];
            unsigned int pos = atomicAdd(&hist[p >> 24], 1u);
            ssrc[pb + (int)pos] = (int)(p & 0xFFFFFFu);
        }
        if (t < 256)
            for (unsigned int k = v; k < v4; ++k) ssrc[pb + (int)(loc2[t] + k)] = n;
    }
}

__device__ inline float4 lrelu4(float4 v) {
    float4 r;
    r.x = v.x >= 0.f ? v.x : 0.2f * v.x;
    r.y = v.y >= 0.f ? v.y : 0.2f * v.y;
    r.z = v.z >= 0.f ? v.z : 0.2f * v.z;
    r.w = v.w >= 0.f ? v.w : 0.2f * v.w;
    return r;
}

// Aligned accumulate over [LO,HI) within chunk starting at s0; two fmac
// chains per node (ACCA/ACCB) to halve dependency stalls.
#define ACCUM(LO, HI, ACCA, ACCB, ZS)                                           \
    {                                                                           \
        int g_ = ((LO) - s0) >> 2, gb_ = ((HI) - s0) >> 2;                      \
        for (; g_ + 4 <= gb_; g_ += 4) {                                        \
            int4 uu0 = *(const int4*)&ub[g_ * 4];                               \
            int4 uu1 = *(const int4*)&ub[g_ * 4 + 4];                           \
            int4 uu2 = *(const int4*)&ub[g_ * 4 + 8];                           \
            int4 uu3 = *(const int4*)&ub[g_ * 4 + 12];                          \
            float4 pp0 = *(const float4*)&per[g_ * 4];                          \
            float4 pp1 = *(const float4*)&per[g_ * 4 + 4];                      \
            float4 pp2 = *(const float4*)&per[g_ * 4 + 8];                      \
            float4 pp3 = *(const float4*)&per[g_ * 4 + 12];                     \
            float x0 = *(const float*)(xl + (size_t)(unsigned)uu0.x);           \
            float x1 = *(const float*)(xl + (size_t)(unsigned)uu0.y);           \
            float x2 = *(const float*)(xl + (size_t)(unsigned)uu0.z);           \
            float x3 = *(const float*)(xl + (size_t)(unsigned)uu0.w);           \
            float x4 = *(const float*)(xl + (size_t)(unsigned)uu1.x);           \
            float x5 = *(const float*)(xl + (size_t)(unsigned)uu1.y);           \
            float x6 = *(const float*)(xl + (size_t)(unsigned)uu1.z);           \
            float x7 = *(const float*)(xl + (size_t)(unsigned)uu1.w);           \
            float x8 = *(const float*)(xl + (size_t)(unsigned)uu2.x);           \
            float x9 = *(const float*)(xl + (size_t)(unsigned)uu2.y);           \
            float xa = *(const float*)(xl + (size_t)(unsigned)uu2.z);           \
            float xb = *(const float*)(xl + (size_t)(unsigned)uu2.w);           \
            float xc = *(const float*)(xl + (size_t)(unsigned)uu3.x);           \
            float xd = *(const float*)(xl + (size_t)(unsigned)uu3.y);           \
            float xe = *(const float*)(xl + (size_t)(unsigned)uu3.z);           \
            float xf = *(const float*)(xl + (size_t)(unsigned)uu3.w);           \
            ZS += pp0.x + pp0.y + pp0.z + pp0.w;                                \
            ZS += pp1.x + pp1.y + pp1.z + pp1.w;                                \
            ZS += pp2.x + pp2.y + pp2.z + pp2.w;                                \
            ZS += pp3.x + pp3.y + pp3.z + pp3.w;                                \
            ACCA += pp0.x * x0; ACCB += pp0.y * x1;                             \
            ACCA += pp0.z * x2; ACCB += pp0.w * x3;                             \
            ACCA += pp1.x * x4; ACCB += pp1.y * x5;                             \
            ACCA += pp1.z * x6; ACCB += pp1.w * x7;                             \
            ACCA += pp2.x * x8; ACCB += pp2.y * x9;                             \
            ACCA += pp2.z * xa; ACCB += pp2.w * xb;                             \
            ACCA += pp3.x * xc; ACCB += pp3.y * xd;                             \
            ACCA += pp3.z * xe; ACCB += pp3.w * xf;                             \
        }                                                                       \
        for (; g_ < gb_; ++g_) {                                                \
            int4 uu = *(const int4*)&ub[g_ * 4];                                \
            float4 pp = *(const float4*)&per[g_ * 4];                           \
            float x0 = *(const float*)(xl + (size_t)(unsigned)uu.x);            \
            float x1 = *(const float*)(xl + (size_t)(unsigned)uu.y);            \
            float x2 = *(const float*)(xl + (size_t)(unsigned)uu.z);            \
            float x3 = *(const float*)(xl + (size_t)(unsigned)uu.w);            \
            ZS += pp.x + pp.y + pp.z + pp.w;                                    \
            ACCA += pp.x * x0; ACCB += pp.y * x1;                               \
            ACCA += pp.z * x2; ACCB += pp.w * x3;                               \
        }                                                                       \
    }

__global__ __launch_bounds__(256) void k_agg(const float* __restrict__ xh,
                                             const float* __restrict__ als, const float* __restrict__ ald,
                                             const float* __restrict__ mvec,
                                             const int* __restrict__ poffs, const int* __restrict__ pend,
                                             const int* __restrict__ ssrc,
                                             const float* __restrict__ bias, float* __restrict__ hout,
                                             const float* __restrict__ outw, const float* __restrict__ outb,
                                             float* __restrict__ fout, int n) {
    __shared__ int s_u[4][64];
    __shared__ float s_pe[4][4][64];  // [wslot][head][edge]
    int wslot = threadIdx.x >> 6;
    int lane = threadIdx.x & 63;
    int w = (blockIdx.x * 256 + threadIdx.x) >> 6;
    int v0 = w << 2;
    if (v0 >= n) return;
    int head = lane >> 4;
    int* ub = s_u[wslot];
    float* per = s_pe[wslot][head];      // read row for my head
    float* pew = &s_pe[wslot][0][lane];  // write base, stride 64 per head

    int vlast = n - 1;
    int last = min(v0 + 3, vlast);
    int4 rr = *(const int4*)(poffs + v0);
    int e3 = pend[last];
    int r0 = rr.x;
    int r1 = (v0 + 1 <= last) ? rr.y : e3;
    int r2 = (v0 + 2 <= last) ? rr.z : e3;
    int r3 = (v0 + 3 <= last) ? rr.w : e3;

    const char* xl = (const char*)(xh + lane);  // lane column folded into base
    // self edges (pe = 1); issued up-front, all independent
    float acc0a = *(const float*)(xl + ((size_t)(unsigned)v0 << 8));
    float acc1a = *(const float*)(xl + ((size_t)(unsigned)min(v0 + 1, vlast) << 8));
    float acc2a = *(const float*)(xl + ((size_t)(unsigned)min(v0 + 2, vlast) << 8));
    float acc3a = *(const float*)(xl + ((size_t)(unsigned)min(v0 + 3, vlast) << 8));
    float acc0b = 0.f, acc1b = 0.f, acc2b = 0.f, acc3b = 0.f;
    float zs0 = 0.f, zs1 = 0.f, zs2 = 0.f, zs3 = 0.f;

    // prefetch chunk 0 (ssrc -> dependent als gather; ald/m by nid)
    int s0 = r0;
    int u_n = n;
    if (s0 < e3) {
        if (lane < e3 - s0) u_n = ssrc[s0 + lane];
    }
    float4 alu_n = *(const float4*)(als + 4 * (size_t)u_n);
    int e_n = s0 + lane;
    int nid_n = min(v0 + (e_n >= r1) + (e_n >= r2) + (e_n >= r3), vlast);
    float4 ald_n = *(const float4*)(ald + 4 * (size_t)nid_n);
    float4 m_n = *(const float4*)(mvec + 4 * (size_t)nid_n);

    while (s0 < e3) {
        int cnt = min(64, e3 - s0);
        // pe for current chunk from prefetched values
        float4 e4 = lrelu4(make_float4(alu_n.x + ald_n.x, alu_n.y + ald_n.y,
                                       alu_n.z + ald_n.z, alu_n.w + ald_n.w));
        float4 pe;
        pe.x = __expf(e4.x - m_n.x);
        pe.y = __expf(e4.y - m_n.y);
        pe.z = __expf(e4.z - m_n.z);
        pe.w = __expf(e4.w - m_n.w);
        ub[lane] = u_n << 8;  // row byte offset; pads point at phantom n
        pew[0] = pe.x;        // transposed stash: bank stride 64 -> 2-way, free
        pew[64] = pe.y;
        pew[128] = pe.z;
        pew[192] = pe.w;
        // issue next chunk's loads before the long accumulate phase
        int s1 = s0 + 64;
        if (s1 < e3) {
            u_n = n;
            if (lane < e3 - s1) u_n = ssrc[s1 + lane];
            alu_n = *(const float4*)(als + 4 * (size_t)u_n);
            int e1 = s1 + lane;
            int nid1 = min(v0 + (e1 >= r1) + (e1 >= r2) + (e1 >= r3), vlast);
            ald_n = *(const float4*)(ald + 4 * (size_t)nid1);
            m_n = *(const float4*)(mvec + 4 * (size_t)nid1);
        }
        // same-wave LDS RAW (in-order DS unit), no barrier needed
        int lim = s0 + cnt;
        int hi0 = min(r1, lim);
        int lo1 = max(r1, s0), hi1 = min(r2, lim);
        int lo2 = max(r2, s0), hi2 = min(r3, lim);
        int lo3 = max(r3, s0);
        ACCUM(s0, hi0, acc0a, acc0b, zs0);
        ACCUM(lo1, hi1, acc1a, acc1b, zs1);
        ACCUM(lo2, hi2, acc2a, acc2b, zs2);
        ACCUM(lo3, lim, acc3a, acc3b, zs3);
        s0 = s1;
    }

    float bl = bias[lane];
    float o0 = fmaxf((acc0a + acc0b) / (1.f + zs0 + 1e-16f) + bl, 0.f);
    float o1 = fmaxf((acc1a + acc1b) / (1.f + zs1 + 1e-16f) + bl, 0.f);
    float o2 = fmaxf((acc2a + acc2b) / (1.f + zs2 + 1e-16f) + bl, 0.f);
    float o3 = fmaxf((acc3a + acc3b) / (1.f + zs3 + 1e-16f) + bl, 0.f);
    if (outw) {
        float ow = outw[lane];
        float ob = outb[0];
        float t0 = o0 * ow, t1 = o1 * ow, t2 = o2 * ow, t3 = o3 * ow;
#pragma unroll
        for (int d = 32; d; d >>= 1) {
            t0 += __shfl_down(t0, d, 64);
            t1 += __shfl_down(t1, d, 64);
            t2 += __shfl_down(t2, d, 64);
            t3 += __shfl_down(t3, d, 64);
        }
        if (lane == 0) {
            fout[v0] = t0 + ob;
            if (v0 + 1 < n) fout[v0 + 1] = t1 + ob;
            if (v0 + 2 < n) fout[v0 + 2] = t2 + ob;
            if (v0 + 3 < n) fout[v0 + 3] = t3 + ob;
        }
    } else {
        hout[((size_t)v0 << 6) + lane] = o0;
        if (v0 + 1 < n) hout[((size_t)(v0 + 1) << 6) + lane] = o1;
        if (v0 + 2 < n) hout[((size_t)(v0 + 2) << 6) + lane] = o2;
        if (v0 + 3 < n) hout[((size_t)(v0 + 3) << 6) + lane] = o3;
    }
}

extern "C" void kernel_launch(void* const* d_in, const int* in_sizes, int n_in,
                              void* d_out, int out_size, void* d_ws, size_t ws_size,
                              hipStream_t stream) {
    const float* x = (const float*)d_in[0];
    const int* ei = (const int*)d_in[1];
    const float* w[3] = {(const float*)d_in[2], (const float*)d_in[6], (const float*)d_in[10]};
    const float* as[3] = {(const float*)d_in[3], (const float*)d_in[7], (const float*)d_in[11]};
    const float* ad[3] = {(const float*)d_in[4], (const float*)d_in[8], (const float*)d_in[12]};
    const float* b[3] = {(const float*)d_in[5], (const float*)d_in[9], (const float*)d_in[13]};
    const float* outw = (const float*)d_in[14];
    const float* outb = (const float*)d_in[15];

    const int N = in_sizes[0] / 128;
    const int E = in_sizes[1] / 2;
    const int* src = ei;
    const int* dst = ei + E;
    const int NB = (N + 255) / 256;           // 391 <= NBMAX
    const int SB = (E + SCHUNK - 1) / SCHUNK; // 391
    const int GB128 = (N + 127) / 128;        // 782
    const int MG1 = (GB128 + 1) / 2;          // 391
    const int MG2 = GB128 - MG1;              // 391

    char* ws = (char*)d_ws;
    auto alloc = [&](size_t bytes) -> void* {
        void* p = (void*)ws;
        ws += (bytes + 255) & ~(size_t)255;
        return p;
    };
    int* bhist = (int*)alloc(NBMAX * 4);
    int* boffs = (int*)alloc((NBMAX + 1) * 4);
    int* bfill = (int*)alloc(NBMAX * 4);
    int* poffs = (int*)alloc((size_t)(N + 8) * 4);
    int* pend = (int*)alloc((size_t)N * 4);
    int* ssrc = (int*)alloc((size_t)(E + NBMAX * PADSLACK + 256) * 4);
    unsigned int* edata = (unsigned int*)alloc((size_t)(E + 64) * 4);  // own slab: mgemm
    // now overlaps edata's live range, so it may no longer alias xh.
    float* xh = (float*)alloc((size_t)(N + 1) * 64 * 4);  // +1: phantom zero row
    float* hbuf = (float*)alloc((size_t)N * 64 * 4);
    float* als = (float*)alloc((size_t)(N + 1) * 4 * 4);  // +1: phantom -1e30
    float* ald = (float*)alloc((size_t)N * 4 * 4);
    float* mvec = (float*)alloc((size_t)N * 4 * 4);
    unsigned short* p0h = (unsigned short*)alloc(8192 * 2);
    unsigned short* p0l = (unsigned short*)alloc(8192 * 2);
    unsigned short* p1h = (unsigned short*)alloc(4096 * 2);
    unsigned short* p1l = (unsigned short*)alloc(4096 * 2);
    unsigned short* p2h = (unsigned short*)alloc(4096 * 2);
    unsigned short* p2l = (unsigned short*)alloc(4096 * 2);

    k_prep<<<9, 256, 0, stream>>>(w[0], w[1], w[2], p0h, p0l, p1h, p1l, p2h, p2l, bhist, als, xh, N);
    k_bhist<<<256, 256, 0, stream>>>(dst, bhist, E);
    k_bscan<<<1, 512, 0, stream>>>(bhist, boffs, bfill, NB, E);
    // CSR scatter || layer-0 GEMM first half (independent workloads)
    k_mix1<<<SB + MG1, 512, 0, stream>>>(src, dst, boffs, bfill, edata, E, SB,
                                         x, p0h, p0l, as[0], ad[0], xh, als, ald, mvec, N);
    // CSR finalize || layer-0 GEMM second half
    k_mix2<<<NB + MG2, 512, 0, stream>>>(edata, boffs, poffs, pend, ssrc, N, NB, MG1,
                                         x, p0h, p0l, as[0], ad[0], xh, als, ald, mvec);

    const int gblocks = (N + 63) / 64;
    const int ablocks = (N + 15) / 16;  // 4 nodes/wave, 4 waves/block

    k_agg<<<ablocks, 256, 0, stream>>>(xh, als, ald, mvec, poffs, pend, ssrc, b[0], hbuf, nullptr, nullptr, nullptr, N);
    k_mgemm<64><<<gblocks, 256, 0, stream>>>(hbuf, p1h, p1l, as[1], ad[1], xh, als, ald, mvec, N);
    k_agg<<<ablocks, 256, 0, stream>>>(xh, als, ald, mvec, poffs, pend, ssrc, b[1], hbuf, nullptr, nullptr, nullptr, N);
    k_mgemm<64><<<gblocks, 256, 0, stream>>>(hbuf, p2h, p2l, as[2], ad[2], xh, als, ald, mvec, N);
    k_agg<<<ablocks, 256, 0, stream>>>(xh, als, ald, mvec, poffs, pend, ssrc, b[2], nullptr, outw, outb, (float*)d_out, N);
}